// Round 1
// baseline (2988.449 us; speedup 1.0000x reference)
//
#include <hip/hip_runtime.h>
#include <math.h>

#define N_NODES 50000
#define N_EDGES 800000
#define DIM 128
#define NEG_SLOPE 0.01f

// ---------------------------------------------------------------------------
// Kernel 1: deg histogram + h_sum = segment_sum(x[src], dst)
// One thread per (edge, 4-float chunk): 32 chunks cover DIM=128.
// Consecutive threads -> same edge row, consecutive float4 -> coalesced gather.
// ---------------------------------------------------------------------------
__global__ __launch_bounds__(256) void k_deg_hsum(
    const float* __restrict__ x, const int* __restrict__ src,
    const int* __restrict__ dst, float* __restrict__ h_sum,
    float* __restrict__ deg)
{
    int g = blockIdx.x * 256 + threadIdx.x;
    int e = g >> 5;
    int c = g & 31;
    if (e >= N_EDGES) return;
    int s = src[e];
    int d = dst[e];
    float4 v = ((const float4*)(x + (size_t)s * DIM))[c];
    float* o = h_sum + (size_t)d * DIM + c * 4;
    unsafeAtomicAdd(o + 0, v.x);
    unsafeAtomicAdd(o + 1, v.y);
    unsafeAtomicAdd(o + 2, v.z);
    unsafeAtomicAdd(o + 3, v.w);
    if (c == 0) unsafeAtomicAdd(deg + d, 1.0f);
}

// ---------------------------------------------------------------------------
// Kernel 2: O = A @ W + b, optionally scaling each input row by 1/max(deg,1).
// Block = 256 threads, tile = 32 rows x 128 cols, 4x4 register tile/thread.
// W staged in LDS in two 64-row halves (32 KB) + transposed x tile (16 KB)
// -> 48 KB LDS, 3 blocks/CU.
// ---------------------------------------------------------------------------
template <bool SCALE>
__global__ __launch_bounds__(256) void k_gemm(
    const float* __restrict__ A, const float* __restrict__ W,
    const float* __restrict__ bias, const float* __restrict__ deg,
    float* __restrict__ O)
{
    __shared__ float Wl[64][DIM];   // 32 KB, Wl[k][c]
    __shared__ float xT[DIM][32];   // 16 KB, xT[k][r]
    int t = threadIdx.x;
    int m0 = blockIdx.x * 32;

    // stage x tile (transposed). thread t handles row (t&31), k-chunks (t>>5)+8j
    {
        int row = t & 31;
        int r = m0 + row;
        for (int kk = (t >> 5); kk < 32; kk += 8) {
            float4 v = make_float4(0.f, 0.f, 0.f, 0.f);
            if (r < N_NODES) {
                v = ((const float4*)(A + (size_t)r * DIM))[kk];
                if (SCALE) {
                    float inv = 1.0f / fmaxf(deg[r], 1.0f);
                    v.x *= inv; v.y *= inv; v.z *= inv; v.w *= inv;
                }
            }
            xT[kk * 4 + 0][row] = v.x;
            xT[kk * 4 + 1][row] = v.y;
            xT[kk * 4 + 2][row] = v.z;
            xT[kk * 4 + 3][row] = v.w;
        }
    }

    int c0 = (t & 31) * 4;   // 32 col-groups of 4
    int r0 = (t >> 5) * 4;   // 8 row-groups of 4
    float acc[4][4] = {};

    float4* Wl4 = (float4*)&Wl[0][0];
    for (int half = 0; half < 2; ++half) {
        __syncthreads();  // also covers the xT staging on first iteration
        const float4* Wsrc = (const float4*)(W + (size_t)half * 64 * DIM);
        for (int i = t; i < 64 * DIM / 4; i += 256) Wl4[i] = Wsrc[i];
        __syncthreads();
        #pragma unroll 8
        for (int k = 0; k < 64; ++k) {
            float4 wv = *(const float4*)&Wl[k][c0];
            float4 xv = *(const float4*)&xT[half * 64 + k][r0];
            acc[0][0] += xv.x * wv.x; acc[0][1] += xv.x * wv.y;
            acc[0][2] += xv.x * wv.z; acc[0][3] += xv.x * wv.w;
            acc[1][0] += xv.y * wv.x; acc[1][1] += xv.y * wv.y;
            acc[1][2] += xv.y * wv.z; acc[1][3] += xv.y * wv.w;
            acc[2][0] += xv.z * wv.x; acc[2][1] += xv.z * wv.y;
            acc[2][2] += xv.z * wv.z; acc[2][3] += xv.z * wv.w;
            acc[3][0] += xv.w * wv.x; acc[3][1] += xv.w * wv.y;
            acc[3][2] += xv.w * wv.z; acc[3][3] += xv.w * wv.w;
        }
    }

    float4 bv = *(const float4*)(bias + c0);
    #pragma unroll
    for (int i = 0; i < 4; ++i) {
        int r = m0 + r0 + i;
        if (r < N_NODES) {
            float4 o;
            o.x = acc[i][0] + bv.x;
            o.y = acc[i][1] + bv.y;
            o.z = acc[i][2] + bv.z;
            o.w = acc[i][3] + bv.w;
            ((float4*)(O + (size_t)r * DIM))[c0 >> 2] = o;
        }
    }
}

// ---------------------------------------------------------------------------
// Kernel 3: per-edge score. 16 lanes/edge, each lane handles 8 features.
// s[e] = exp(dot(leaky_relu(ha_src[src]+ha_dst[dst]), att_w) + att_b);
// denom[dst] += s[e].
// ---------------------------------------------------------------------------
__global__ __launch_bounds__(256) void k_score(
    const float* __restrict__ ha_s, const float* __restrict__ ha_d,
    const int* __restrict__ src, const int* __restrict__ dst,
    const float* __restrict__ att_w, const float* __restrict__ att_b,
    float* __restrict__ sarr, float* __restrict__ denom)
{
    __shared__ float aw[DIM];
    int t = threadIdx.x;
    if (t < DIM) aw[t] = att_w[t];
    __syncthreads();

    int e = blockIdx.x * 16 + (t >> 4);
    int lane = t & 15;
    if (e >= N_EDGES) return;
    int s = src[e];
    int d = dst[e];
    const float4* as4 = (const float4*)(ha_s + (size_t)s * DIM);
    const float4* ad4 = (const float4*)(ha_d + (size_t)d * DIM);
    const float4* aw4 = (const float4*)aw;

    float p = 0.f;
    #pragma unroll
    for (int j = 0; j < 2; ++j) {
        int idx = lane * 2 + j;
        float4 a = as4[idx];
        float4 b = ad4[idx];
        float4 w = aw4[idx];
        float v;
        v = a.x + b.x; v = (v > 0.f) ? v : v * NEG_SLOPE; p += v * w.x;
        v = a.y + b.y; v = (v > 0.f) ? v : v * NEG_SLOPE; p += v * w.y;
        v = a.z + b.z; v = (v > 0.f) ? v : v * NEG_SLOPE; p += v * w.z;
        v = a.w + b.w; v = (v > 0.f) ? v : v * NEG_SLOPE; p += v * w.w;
    }
    p += __shfl_xor(p, 8, 16);
    p += __shfl_xor(p, 4, 16);
    p += __shfl_xor(p, 2, 16);
    p += __shfl_xor(p, 1, 16);
    if (lane == 0) {
        float sv = expf(p + att_b[0]);
        sarr[e] = sv;
        unsafeAtomicAdd(denom + d, sv);
    }
}

// ---------------------------------------------------------------------------
// Kernel 4: denom -> 1/denom (0 for untouched nodes; those are never read)
// ---------------------------------------------------------------------------
__global__ __launch_bounds__(256) void k_recip(float* __restrict__ denom)
{
    int i = blockIdx.x * 256 + threadIdx.x;
    if (i < N_NODES) {
        float v = denom[i];
        denom[i] = (v > 0.f) ? (1.0f / v) : 0.f;
    }
}

// ---------------------------------------------------------------------------
// Kernel 5: out[dst] += x[src] * (s[e] * rdenom[dst])
// Same (edge, chunk) layout as kernel 1.
// ---------------------------------------------------------------------------
__global__ __launch_bounds__(256) void k_out(
    const float* __restrict__ x, const int* __restrict__ src,
    const int* __restrict__ dst, const float* __restrict__ sarr,
    const float* __restrict__ rden, float* __restrict__ out)
{
    int g = blockIdx.x * 256 + threadIdx.x;
    int e = g >> 5;
    int c = g & 31;
    if (e >= N_EDGES) return;
    int s = src[e];
    int d = dst[e];
    float a = sarr[e] * rden[d];
    float4 v = ((const float4*)(x + (size_t)s * DIM))[c];
    float* o = out + (size_t)d * DIM + c * 4;
    unsafeAtomicAdd(o + 0, v.x * a);
    unsafeAtomicAdd(o + 1, v.y * a);
    unsafeAtomicAdd(o + 2, v.z * a);
    unsafeAtomicAdd(o + 3, v.w * a);
}

// ---------------------------------------------------------------------------
extern "C" void kernel_launch(void* const* d_in, const int* in_sizes, int n_in,
                              void* d_out, int out_size, void* d_ws, size_t ws_size,
                              hipStream_t stream)
{
    const float* x     = (const float*)d_in[0];
    const int*   src   = (const int*)d_in[1];
    const int*   dst   = (const int*)d_in[2];
    const float* src_w = (const float*)d_in[3];
    const float* src_b = (const float*)d_in[4];
    const float* dst_w = (const float*)d_in[5];
    const float* dst_b = (const float*)d_in[6];
    const float* att_w = (const float*)d_in[7];
    const float* att_b = (const float*)d_in[8];
    float* out = (float*)d_out;

    const size_t NF = (size_t)N_NODES * DIM;   // 6,400,000
    const size_t NPAD = 50176;                  // padded node-scalar arrays
    float* ws = (float*)d_ws;
    size_t off = 0;
    float* deg    = ws + off; off += NPAD;
    float* h_sum  = ws + off; off += NF;
    float* ha_src = ws + off; off += NF;
    float* ha_dst = ws + off; off += NF;
    float* sarr   = ws + off; off += (size_t)N_EDGES;
    float* denom  = ws + off; off += NPAD;
    (void)ws_size; (void)in_sizes; (void)n_in; (void)out_size;

    // zero accumulators (deg and h_sum are contiguous -> single memset)
    hipMemsetAsync(deg, 0, (NPAD + NF) * sizeof(float), stream);
    hipMemsetAsync(denom, 0, NPAD * sizeof(float), stream);
    hipMemsetAsync(out, 0, NF * sizeof(float), stream);

    // 1) degree + mean-aggregation numerator
    k_deg_hsum<<<(N_EDGES * 32) / 256, 256, 0, stream>>>(x, src, dst, h_sum, deg);

    // 2) attention projections
    int gemm_blocks = (N_NODES + 31) / 32;
    k_gemm<false><<<gemm_blocks, 256, 0, stream>>>(x, src_w, src_b, nullptr, ha_src);
    k_gemm<true ><<<gemm_blocks, 256, 0, stream>>>(h_sum, dst_w, dst_b, deg, ha_dst);

    // 3) per-edge scores + softmax denominator
    k_score<<<N_EDGES / 16, 256, 0, stream>>>(ha_src, ha_dst, src, dst,
                                              att_w, att_b, sarr, denom);

    // 4) reciprocal of denominator
    k_recip<<<(N_NODES + 255) / 256, 256, 0, stream>>>(denom);

    // 5) weighted scatter-sum
    k_out<<<(N_EDGES * 32) / 256, 256, 0, stream>>>(x, src, dst, sarr, denom, out);
}

// Round 2
// 447.856 us; speedup vs baseline: 6.6728x; 6.6728x over previous
//
#include <hip/hip_runtime.h>
#include <math.h>

#define N_NODES 50000
#define N_EDGES 800000
#define DIM 128
#define NEG_SLOPE 0.01f
#define NB 196   // ceil(N_NODES/256)

// ---------------------------------------------------------------------------
// CSR build: histogram -> 3-kernel exclusive scan -> scatter.
// After k_scatter, rs[n] = END of node n's segment (start = end - deg[n]).
// ---------------------------------------------------------------------------
__global__ __launch_bounds__(256) void k_hist(const int* __restrict__ dst,
                                              int* __restrict__ deg)
{
    int e = blockIdx.x * 256 + threadIdx.x;
    if (e < N_EDGES) atomicAdd(&deg[dst[e]], 1);
}

__global__ __launch_bounds__(256) void k_scan1(const int* __restrict__ deg,
                                               int* __restrict__ bsum)
{
    __shared__ int sm[256];
    int t = threadIdx.x;
    int i = blockIdx.x * 256 + t;
    sm[t] = (i < N_NODES) ? deg[i] : 0;
    __syncthreads();
    for (int o = 128; o > 0; o >>= 1) {
        if (t < o) sm[t] += sm[t + o];
        __syncthreads();
    }
    if (t == 0) bsum[blockIdx.x] = sm[0];
}

__global__ __launch_bounds__(256) void k_scan2(int* __restrict__ bsum)
{
    __shared__ int sm[256];
    int t = threadIdx.x;
    int v = (t < NB) ? bsum[t] : 0;
    sm[t] = v;
    __syncthreads();
    for (int o = 1; o < 256; o <<= 1) {
        int u = (t >= o) ? sm[t - o] : 0;
        __syncthreads();
        sm[t] += u;
        __syncthreads();
    }
    if (t < NB) bsum[t] = sm[t] - v;   // exclusive of block sums, in place
}

__global__ __launch_bounds__(256) void k_scan3(const int* __restrict__ deg,
                                               const int* __restrict__ bsum,
                                               int* __restrict__ rs)
{
    __shared__ int sm[256];
    int t = threadIdx.x;
    int i = blockIdx.x * 256 + t;
    int v = (i < N_NODES) ? deg[i] : 0;
    sm[t] = v;
    __syncthreads();
    for (int o = 1; o < 256; o <<= 1) {
        int u = (t >= o) ? sm[t - o] : 0;
        __syncthreads();
        sm[t] += u;
        __syncthreads();
    }
    if (i < N_NODES) rs[i] = bsum[blockIdx.x] + sm[t] - v;  // exclusive start
}

__global__ __launch_bounds__(256) void k_scatter(const int* __restrict__ src,
                                                 const int* __restrict__ dst,
                                                 int* __restrict__ rs,
                                                 int* __restrict__ srcs)
{
    int e = blockIdx.x * 256 + threadIdx.x;
    if (e >= N_EDGES) return;
    int pos = atomicAdd(&rs[dst[e]], 1);
    srcs[pos] = src[e];
}

// ---------------------------------------------------------------------------
// Mean aggregation: one 64-lane wave per node, float2 per lane (128 floats).
// ---------------------------------------------------------------------------
__global__ __launch_bounds__(256) void k_hmean(
    const float* __restrict__ x, const int* __restrict__ srcs,
    const int* __restrict__ rs_end, const int* __restrict__ deg,
    float* __restrict__ h_mean)
{
    int g = blockIdx.x * 256 + threadIdx.x;
    int node = g >> 6;
    int lane = g & 63;
    if (node >= N_NODES) return;
    int end = rs_end[node];
    int cnt = deg[node];
    int i = end - cnt;
    const float2* xp = (const float2*)x;
    float2 acc = make_float2(0.f, 0.f);
    for (; i + 1 < end; i += 2) {       // 2-way unroll for load ILP
        int s0 = srcs[i];
        int s1 = srcs[i + 1];
        float2 a = xp[s0 * 64 + lane];
        float2 b = xp[s1 * 64 + lane];
        acc.x += a.x + b.x;
        acc.y += a.y + b.y;
    }
    if (i < end) {
        int s0 = srcs[i];
        float2 a = xp[s0 * 64 + lane];
        acc.x += a.x;
        acc.y += a.y;
    }
    float inv = 1.0f / (float)max(cnt, 1);
    float2 o;
    o.x = acc.x * inv;
    o.y = acc.y * inv;
    ((float2*)h_mean)[node * 64 + lane] = o;
}

// ---------------------------------------------------------------------------
// GEMM: O = A @ W + b. Block = 256 threads, tile = 32 rows x 128 cols,
// 4x4 register tile/thread. (Unchanged from R1 except deg-scaling removed.)
// ---------------------------------------------------------------------------
__global__ __launch_bounds__(256) void k_gemm(
    const float* __restrict__ A, const float* __restrict__ W,
    const float* __restrict__ bias, float* __restrict__ O)
{
    __shared__ float Wl[64][DIM];   // 32 KB
    __shared__ float xT[DIM][32];   // 16 KB
    int t = threadIdx.x;
    int m0 = blockIdx.x * 32;

    {
        int row = t & 31;
        int r = m0 + row;
        for (int kk = (t >> 5); kk < 32; kk += 8) {
            float4 v = make_float4(0.f, 0.f, 0.f, 0.f);
            if (r < N_NODES) v = ((const float4*)(A + (size_t)r * DIM))[kk];
            xT[kk * 4 + 0][row] = v.x;
            xT[kk * 4 + 1][row] = v.y;
            xT[kk * 4 + 2][row] = v.z;
            xT[kk * 4 + 3][row] = v.w;
        }
    }

    int c0 = (t & 31) * 4;
    int r0 = (t >> 5) * 4;
    float acc[4][4] = {};

    float4* Wl4 = (float4*)&Wl[0][0];
    for (int half = 0; half < 2; ++half) {
        __syncthreads();
        const float4* Wsrc = (const float4*)(W + (size_t)half * 64 * DIM);
        for (int i = t; i < 64 * DIM / 4; i += 256) Wl4[i] = Wsrc[i];
        __syncthreads();
        #pragma unroll 8
        for (int k = 0; k < 64; ++k) {
            float4 wv = *(const float4*)&Wl[k][c0];
            float4 xv = *(const float4*)&xT[half * 64 + k][r0];
            acc[0][0] += xv.x * wv.x; acc[0][1] += xv.x * wv.y;
            acc[0][2] += xv.x * wv.z; acc[0][3] += xv.x * wv.w;
            acc[1][0] += xv.y * wv.x; acc[1][1] += xv.y * wv.y;
            acc[1][2] += xv.y * wv.z; acc[1][3] += xv.y * wv.w;
            acc[2][0] += xv.z * wv.x; acc[2][1] += xv.z * wv.y;
            acc[2][2] += xv.z * wv.z; acc[2][3] += xv.z * wv.w;
            acc[3][0] += xv.w * wv.x; acc[3][1] += xv.w * wv.y;
            acc[3][2] += xv.w * wv.z; acc[3][3] += xv.w * wv.w;
        }
    }

    float4 bv = *(const float4*)(bias + c0);
    #pragma unroll
    for (int i = 0; i < 4; ++i) {
        int r = m0 + r0 + i;
        if (r < N_NODES) {
            float4 o;
            o.x = acc[i][0] + bv.x;
            o.y = acc[i][1] + bv.y;
            o.z = acc[i][2] + bv.z;
            o.w = acc[i][3] + bv.w;
            ((float4*)(O + (size_t)r * DIM))[c0 >> 2] = o;
        }
    }
}

// ---------------------------------------------------------------------------
// Fused score + edge-softmax + weighted aggregation.
// One wave per destination node: for each incoming edge, compute
// s = exp(dot(leaky_relu(ha_src[src] + ha_dst[node]), att_w) + att_b),
// accumulate acc += s * x[src], dsum += s; write acc/dsum.
// ---------------------------------------------------------------------------
__global__ __launch_bounds__(256) void k_out_fused(
    const float* __restrict__ x, const float* __restrict__ ha_s,
    const float* __restrict__ ha_d, const int* __restrict__ srcs,
    const int* __restrict__ rs_end, const int* __restrict__ deg,
    const float* __restrict__ att_w, const float* __restrict__ att_b,
    float* __restrict__ out)
{
    int g = blockIdx.x * 256 + threadIdx.x;
    int node = g >> 6;
    int lane = g & 63;
    if (node >= N_NODES) return;
    int end = rs_end[node];
    int cnt = deg[node];
    float2 o2 = make_float2(0.f, 0.f);
    if (cnt == 0) {                      // no incoming edges: out row = 0
        ((float2*)out)[node * 64 + lane] = o2;
        return;
    }
    int i = end - cnt;
    const float2* xp  = (const float2*)x;
    const float2* hsp = (const float2*)ha_s;
    float2 hd = ((const float2*)ha_d)[node * 64 + lane];
    float2 aw = ((const float2*)att_w)[lane];
    float ab = att_b[0];
    float dsum = 0.f;
    for (; i < end; ++i) {
        int s = srcs[i];
        float2 hs = hsp[s * 64 + lane];
        float2 xv = xp[s * 64 + lane];
        float v0 = hs.x + hd.x; v0 = (v0 > 0.f) ? v0 : v0 * NEG_SLOPE;
        float v1 = hs.y + hd.y; v1 = (v1 > 0.f) ? v1 : v1 * NEG_SLOPE;
        float p = v0 * aw.x + v1 * aw.y;
        p += __shfl_xor(p, 32);
        p += __shfl_xor(p, 16);
        p += __shfl_xor(p, 8);
        p += __shfl_xor(p, 4);
        p += __shfl_xor(p, 2);
        p += __shfl_xor(p, 1);
        float sv = __expf(p + ab);
        o2.x += sv * xv.x;
        o2.y += sv * xv.y;
        dsum += sv;
    }
    float inv = 1.0f / dsum;
    o2.x *= inv;
    o2.y *= inv;
    ((float2*)out)[node * 64 + lane] = o2;
}

// ---------------------------------------------------------------------------
extern "C" void kernel_launch(void* const* d_in, const int* in_sizes, int n_in,
                              void* d_out, int out_size, void* d_ws, size_t ws_size,
                              hipStream_t stream)
{
    const float* x     = (const float*)d_in[0];
    const int*   src   = (const int*)d_in[1];
    const int*   dst   = (const int*)d_in[2];
    const float* src_w = (const float*)d_in[3];
    const float* src_b = (const float*)d_in[4];
    const float* dst_w = (const float*)d_in[5];
    const float* dst_b = (const float*)d_in[6];
    const float* att_w = (const float*)d_in[7];
    const float* att_b = (const float*)d_in[8];
    float* out = (float*)d_out;
    (void)in_sizes; (void)n_in; (void)out_size; (void)ws_size;

    const size_t NF = (size_t)N_NODES * DIM;

    // workspace layout (4-byte words; all offsets divisible by 4 -> 16B aligned)
    int* ws = (int*)d_ws;
    int* ideg = ws;                         // 50000
    int* rs   = ws + 50000;                 // 50000  (becomes segment END after scatter)
    int* bsum = ws + 100000;                // 196
    int* srcs = ws + 100196;                // 800000
    float* h_mean = (float*)(ws + 900196);  // 6.4M
    float* ha_src = h_mean + NF;            // 6.4M
    float* ha_dst = ha_src + NF;            // 6.4M

    hipMemsetAsync(ideg, 0, N_NODES * sizeof(int), stream);

    // CSR build
    k_hist   <<<N_EDGES / 256, 256, 0, stream>>>(dst, ideg);
    k_scan1  <<<NB, 256, 0, stream>>>(ideg, bsum);
    k_scan2  <<<1, 256, 0, stream>>>(bsum);
    k_scan3  <<<NB, 256, 0, stream>>>(ideg, bsum, rs);
    k_scatter<<<N_EDGES / 256, 256, 0, stream>>>(src, dst, rs, srcs);

    // mean aggregation (wave per node)
    k_hmean<<<N_NODES * 64 / 256, 256, 0, stream>>>(x, srcs, rs, ideg, h_mean);

    // attention projections
    int gemm_blocks = (N_NODES + 31) / 32;
    k_gemm<<<gemm_blocks, 256, 0, stream>>>(x, src_w, src_b, ha_src);
    k_gemm<<<gemm_blocks, 256, 0, stream>>>(h_mean, dst_w, dst_b, ha_dst);

    // fused score + softmax + weighted aggregation (wave per node)
    k_out_fused<<<N_NODES * 64 / 256, 256, 0, stream>>>(
        x, ha_src, ha_dst, srcs, rs, ideg, att_w, att_b, out);
}

// Round 3
// 377.417 us; speedup vs baseline: 7.9182x; 1.1866x over previous
//
#include <hip/hip_runtime.h>
#include <math.h>

#define N_NODES 50000
#define N_EDGES 800000
#define DIM 128
#define NEG_SLOPE 0.01f
#define NB 196   // ceil(N_NODES/256)

// ---- bf16 helpers (manual RNE pack, shift unpack) -------------------------
__device__ inline unsigned f2bf2(float a, float b) {
    unsigned ua = __float_as_uint(a);
    unsigned ub = __float_as_uint(b);
    ua = (ua + 0x7fffu + ((ua >> 16) & 1u)) >> 16;
    ub = (ub + 0x7fffu + ((ub >> 16) & 1u)) & 0xffff0000u;
    return ua | ub;
}
__device__ inline float2 bf2f(unsigned u) {
    float2 r;
    r.x = __uint_as_float(u << 16);
    r.y = __uint_as_float(u & 0xffff0000u);
    return r;
}

// ---------------------------------------------------------------------------
// x (fp32) -> xh (bf16 pairs packed in uint). 4 floats / thread.
// ---------------------------------------------------------------------------
__global__ __launch_bounds__(256) void k_cvt(const float* __restrict__ x,
                                             unsigned* __restrict__ xh)
{
    int i = blockIdx.x * 256 + threadIdx.x;   // over NF/4 = 1.6M
    float4 v = ((const float4*)x)[i];
    uint2 o;
    o.x = f2bf2(v.x, v.y);
    o.y = f2bf2(v.z, v.w);
    ((uint2*)xh)[i] = o;
}

// ---------------------------------------------------------------------------
// CSR build: histogram -> 3-kernel exclusive scan -> scatter.
// After k_scatter, rs[n] = END of node n's segment (start = end - deg[n]).
// ---------------------------------------------------------------------------
__global__ __launch_bounds__(256) void k_hist(const int* __restrict__ dst,
                                              int* __restrict__ deg)
{
    int e = blockIdx.x * 256 + threadIdx.x;
    if (e < N_EDGES) atomicAdd(&deg[dst[e]], 1);
}

__global__ __launch_bounds__(256) void k_scan1(const int* __restrict__ deg,
                                               int* __restrict__ bsum)
{
    __shared__ int sm[256];
    int t = threadIdx.x;
    int i = blockIdx.x * 256 + t;
    sm[t] = (i < N_NODES) ? deg[i] : 0;
    __syncthreads();
    for (int o = 128; o > 0; o >>= 1) {
        if (t < o) sm[t] += sm[t + o];
        __syncthreads();
    }
    if (t == 0) bsum[blockIdx.x] = sm[0];
}

__global__ __launch_bounds__(256) void k_scan2(int* __restrict__ bsum)
{
    __shared__ int sm[256];
    int t = threadIdx.x;
    int v = (t < NB) ? bsum[t] : 0;
    sm[t] = v;
    __syncthreads();
    for (int o = 1; o < 256; o <<= 1) {
        int u = (t >= o) ? sm[t - o] : 0;
        __syncthreads();
        sm[t] += u;
        __syncthreads();
    }
    if (t < NB) bsum[t] = sm[t] - v;   // exclusive of block sums, in place
}

__global__ __launch_bounds__(256) void k_scan3(const int* __restrict__ deg,
                                               const int* __restrict__ bsum,
                                               int* __restrict__ rs)
{
    __shared__ int sm[256];
    int t = threadIdx.x;
    int i = blockIdx.x * 256 + t;
    int v = (i < N_NODES) ? deg[i] : 0;
    sm[t] = v;
    __syncthreads();
    for (int o = 1; o < 256; o <<= 1) {
        int u = (t >= o) ? sm[t - o] : 0;
        __syncthreads();
        sm[t] += u;
        __syncthreads();
    }
    if (i < N_NODES) rs[i] = bsum[blockIdx.x] + sm[t] - v;  // exclusive start
}

__global__ __launch_bounds__(256) void k_scatter(const int* __restrict__ src,
                                                 const int* __restrict__ dst,
                                                 int* __restrict__ rs,
                                                 int* __restrict__ srcs)
{
    int e = blockIdx.x * 256 + threadIdx.x;
    if (e >= N_EDGES) return;
    int pos = atomicAdd(&rs[dst[e]], 1);
    srcs[pos] = src[e];
}

// ---------------------------------------------------------------------------
// Mean aggregation: one 64-lane wave per node, bf16x2 (4 B) per lane.
// 4-way edge unroll for gather MLP. Output fp32 (GEMM input).
// ---------------------------------------------------------------------------
__global__ __launch_bounds__(256) void k_hmean(
    const unsigned* __restrict__ xh, const int* __restrict__ srcs,
    const int* __restrict__ rs_end, const int* __restrict__ deg,
    float* __restrict__ h_mean)
{
    int g = blockIdx.x * 256 + threadIdx.x;
    int node = g >> 6;
    int lane = g & 63;
    if (node >= N_NODES) return;
    int end = rs_end[node];
    int cnt = deg[node];
    int i = end - cnt;
    float2 acc = make_float2(0.f, 0.f);
    for (; i + 3 < end; i += 4) {
        unsigned u0 = xh[srcs[i] * 64 + lane];
        unsigned u1 = xh[srcs[i + 1] * 64 + lane];
        unsigned u2 = xh[srcs[i + 2] * 64 + lane];
        unsigned u3 = xh[srcs[i + 3] * 64 + lane];
        float2 a = bf2f(u0), b = bf2f(u1), c = bf2f(u2), d = bf2f(u3);
        acc.x += (a.x + b.x) + (c.x + d.x);
        acc.y += (a.y + b.y) + (c.y + d.y);
    }
    for (; i < end; ++i) {
        float2 a = bf2f(xh[srcs[i] * 64 + lane]);
        acc.x += a.x;
        acc.y += a.y;
    }
    float inv = 1.0f / (float)max(cnt, 1);
    float2 o;
    o.x = acc.x * inv;
    o.y = acc.y * inv;
    ((float2*)h_mean)[node * 64 + lane] = o;
}

// ---------------------------------------------------------------------------
// GEMM: O(bf16) = A(fp32) @ W + b. Block = 256, tile = 32 rows x 128 cols,
// 4x4 register tile/thread, fp32 accumulate.
// ---------------------------------------------------------------------------
__global__ __launch_bounds__(256) void k_gemm(
    const float* __restrict__ A, const float* __restrict__ W,
    const float* __restrict__ bias, unsigned* __restrict__ O)
{
    __shared__ float Wl[64][DIM];   // 32 KB
    __shared__ float xT[DIM][32];   // 16 KB
    int t = threadIdx.x;
    int m0 = blockIdx.x * 32;

    {
        int row = t & 31;
        int r = m0 + row;
        for (int kk = (t >> 5); kk < 32; kk += 8) {
            float4 v = make_float4(0.f, 0.f, 0.f, 0.f);
            if (r < N_NODES) v = ((const float4*)(A + (size_t)r * DIM))[kk];
            xT[kk * 4 + 0][row] = v.x;
            xT[kk * 4 + 1][row] = v.y;
            xT[kk * 4 + 2][row] = v.z;
            xT[kk * 4 + 3][row] = v.w;
        }
    }

    int c0 = (t & 31) * 4;
    int r0 = (t >> 5) * 4;
    float acc[4][4] = {};

    float4* Wl4 = (float4*)&Wl[0][0];
    for (int half = 0; half < 2; ++half) {
        __syncthreads();
        const float4* Wsrc = (const float4*)(W + (size_t)half * 64 * DIM);
        for (int i = t; i < 64 * DIM / 4; i += 256) Wl4[i] = Wsrc[i];
        __syncthreads();
        #pragma unroll 8
        for (int k = 0; k < 64; ++k) {
            float4 wv = *(const float4*)&Wl[k][c0];
            float4 xv = *(const float4*)&xT[half * 64 + k][r0];
            acc[0][0] += xv.x * wv.x; acc[0][1] += xv.x * wv.y;
            acc[0][2] += xv.x * wv.z; acc[0][3] += xv.x * wv.w;
            acc[1][0] += xv.y * wv.x; acc[1][1] += xv.y * wv.y;
            acc[1][2] += xv.y * wv.z; acc[1][3] += xv.y * wv.w;
            acc[2][0] += xv.z * wv.x; acc[2][1] += xv.z * wv.y;
            acc[2][2] += xv.z * wv.z; acc[2][3] += xv.z * wv.w;
            acc[3][0] += xv.w * wv.x; acc[3][1] += xv.w * wv.y;
            acc[3][2] += xv.w * wv.z; acc[3][3] += xv.w * wv.w;
        }
    }

    float4 bv = *(const float4*)(bias + c0);
    #pragma unroll
    for (int i = 0; i < 4; ++i) {
        int r = m0 + r0 + i;
        if (r < N_NODES) {
            uint2 o;
            o.x = f2bf2(acc[i][0] + bv.x, acc[i][1] + bv.y);
            o.y = f2bf2(acc[i][2] + bv.z, acc[i][3] + bv.w);
            ((uint2*)(O + (size_t)r * 64))[c0 >> 2] = o;
        }
    }
}

// ---------------------------------------------------------------------------
// Fused score + edge-softmax + weighted aggregation, bf16 gathers.
// One wave per destination node, 2-edge unroll for load/shuffle ILP.
// ---------------------------------------------------------------------------
__global__ __launch_bounds__(256) void k_out_fused(
    const unsigned* __restrict__ xh, const unsigned* __restrict__ ha_s,
    const unsigned* __restrict__ ha_d, const int* __restrict__ srcs,
    const int* __restrict__ rs_end, const int* __restrict__ deg,
    const float* __restrict__ att_w, const float* __restrict__ att_b,
    float* __restrict__ out)
{
    int g = blockIdx.x * 256 + threadIdx.x;
    int node = g >> 6;
    int lane = g & 63;
    if (node >= N_NODES) return;
    int end = rs_end[node];
    int cnt = deg[node];
    float2 o2 = make_float2(0.f, 0.f);
    if (cnt == 0) {
        ((float2*)out)[node * 64 + lane] = o2;
        return;
    }
    int i = end - cnt;
    float2 hd = bf2f(ha_d[node * 64 + lane]);
    float2 aw = ((const float2*)att_w)[lane];
    float ab = att_b[0];
    float dsum = 0.f;

    for (; i + 1 < end; i += 2) {
        int s0 = srcs[i];
        int s1 = srcs[i + 1];
        unsigned uh0 = ha_s[s0 * 64 + lane];
        unsigned uh1 = ha_s[s1 * 64 + lane];
        unsigned ux0 = xh[s0 * 64 + lane];
        unsigned ux1 = xh[s1 * 64 + lane];
        float2 h0 = bf2f(uh0);
        float2 h1 = bf2f(uh1);
        float v00 = h0.x + hd.x; v00 = (v00 > 0.f) ? v00 : v00 * NEG_SLOPE;
        float v01 = h0.y + hd.y; v01 = (v01 > 0.f) ? v01 : v01 * NEG_SLOPE;
        float v10 = h1.x + hd.x; v10 = (v10 > 0.f) ? v10 : v10 * NEG_SLOPE;
        float v11 = h1.y + hd.y; v11 = (v11 > 0.f) ? v11 : v11 * NEG_SLOPE;
        float p0 = v00 * aw.x + v01 * aw.y;
        float p1 = v10 * aw.x + v11 * aw.y;
        p0 += __shfl_xor(p0, 32); p1 += __shfl_xor(p1, 32);
        p0 += __shfl_xor(p0, 16); p1 += __shfl_xor(p1, 16);
        p0 += __shfl_xor(p0, 8);  p1 += __shfl_xor(p1, 8);
        p0 += __shfl_xor(p0, 4);  p1 += __shfl_xor(p1, 4);
        p0 += __shfl_xor(p0, 2);  p1 += __shfl_xor(p1, 2);
        p0 += __shfl_xor(p0, 1);  p1 += __shfl_xor(p1, 1);
        float sv0 = __expf(p0 + ab);
        float sv1 = __expf(p1 + ab);
        float2 x0 = bf2f(ux0);
        float2 x1 = bf2f(ux1);
        o2.x += sv0 * x0.x + sv1 * x1.x;
        o2.y += sv0 * x0.y + sv1 * x1.y;
        dsum += sv0 + sv1;
    }
    if (i < end) {
        int s0 = srcs[i];
        float2 h0 = bf2f(ha_s[s0 * 64 + lane]);
        float2 x0 = bf2f(xh[s0 * 64 + lane]);
        float v00 = h0.x + hd.x; v00 = (v00 > 0.f) ? v00 : v00 * NEG_SLOPE;
        float v01 = h0.y + hd.y; v01 = (v01 > 0.f) ? v01 : v01 * NEG_SLOPE;
        float p0 = v00 * aw.x + v01 * aw.y;
        p0 += __shfl_xor(p0, 32);
        p0 += __shfl_xor(p0, 16);
        p0 += __shfl_xor(p0, 8);
        p0 += __shfl_xor(p0, 4);
        p0 += __shfl_xor(p0, 2);
        p0 += __shfl_xor(p0, 1);
        float sv0 = __expf(p0 + ab);
        o2.x += sv0 * x0.x;
        o2.y += sv0 * x0.y;
        dsum += sv0;
    }
    float inv = 1.0f / dsum;
    o2.x *= inv;
    o2.y *= inv;
    ((float2*)out)[node * 64 + lane] = o2;
}

// ---------------------------------------------------------------------------
extern "C" void kernel_launch(void* const* d_in, const int* in_sizes, int n_in,
                              void* d_out, int out_size, void* d_ws, size_t ws_size,
                              hipStream_t stream)
{
    const float* x     = (const float*)d_in[0];
    const int*   src   = (const int*)d_in[1];
    const int*   dst   = (const int*)d_in[2];
    const float* src_w = (const float*)d_in[3];
    const float* src_b = (const float*)d_in[4];
    const float* dst_w = (const float*)d_in[5];
    const float* dst_b = (const float*)d_in[6];
    const float* att_w = (const float*)d_in[7];
    const float* att_b = (const float*)d_in[8];
    float* out = (float*)d_out;
    (void)in_sizes; (void)n_in; (void)out_size; (void)ws_size;

    const size_t NF = (size_t)N_NODES * DIM;   // 6.4M
    const size_t NF2 = NF / 2;                 // uint count for bf16 arrays

    // workspace layout (4-byte words)
    int* ws = (int*)d_ws;
    int* ideg = ws;                              // 50000
    int* rs   = ws + 50000;                      // 50000 (END after scatter)
    int* bsum = ws + 100000;                     // 196
    int* srcs = ws + 100200;                     // 800000 (start kept 8B-aligned)
    float* h_mean   = (float*)(ws + 900200);     // 6.4M fp32
    unsigned* xh    = (unsigned*)(h_mean + NF);  // 3.2M uint (bf16 x)
    unsigned* ha_s  = xh + NF2;                  // 3.2M uint
    unsigned* ha_d  = ha_s + NF2;                // 3.2M uint

    hipMemsetAsync(ideg, 0, N_NODES * sizeof(int), stream);

    // bf16 copy of x
    k_cvt<<<(int)(NF / 4 / 256), 256, 0, stream>>>(x, xh);

    // CSR build
    k_hist   <<<N_EDGES / 256, 256, 0, stream>>>(dst, ideg);
    k_scan1  <<<NB, 256, 0, stream>>>(ideg, bsum);
    k_scan2  <<<1, 256, 0, stream>>>(bsum);
    k_scan3  <<<NB, 256, 0, stream>>>(ideg, bsum, rs);
    k_scatter<<<N_EDGES / 256, 256, 0, stream>>>(src, dst, rs, srcs);

    // mean aggregation (wave per node, bf16 gathers)
    k_hmean<<<N_NODES * 64 / 256, 256, 0, stream>>>(xh, srcs, rs, ideg, h_mean);

    // attention projections (fp32 in, bf16 out)
    int gemm_blocks = (N_NODES + 31) / 32;
    k_gemm<<<gemm_blocks, 256, 0, stream>>>(x, src_w, src_b, ha_s);
    k_gemm<<<gemm_blocks, 256, 0, stream>>>(h_mean, dst_w, dst_b, ha_d);

    // fused score + softmax + weighted aggregation
    k_out_fused<<<N_NODES * 64 / 256, 256, 0, stream>>>(
        xh, ha_s, ha_d, srcs, rs, ideg, att_w, att_b, out);
}

// Round 4
// 338.894 us; speedup vs baseline: 8.8182x; 1.1137x over previous
//
#include <hip/hip_runtime.h>
#include <math.h>

#define N_NODES 50000
#define N_EDGES 800000
#define DIM 128
#define NEG_SLOPE 0.01f
#define NB 196   // ceil(N_NODES/256)

typedef short v8s __attribute__((ext_vector_type(8)));
typedef float v4f __attribute__((ext_vector_type(4)));

// ---- bf16 helpers (RNE) ---------------------------------------------------
__device__ inline unsigned short f2bf(float a) {
    unsigned u = __float_as_uint(a);
    return (unsigned short)((u + 0x7fffu + ((u >> 16) & 1u)) >> 16);
}
__device__ inline unsigned f2bf2(float a, float b) {
    unsigned ua = __float_as_uint(a);
    unsigned ub = __float_as_uint(b);
    ua = (ua + 0x7fffu + ((ua >> 16) & 1u)) >> 16;
    ub = (ub + 0x7fffu + ((ub >> 16) & 1u)) & 0xffff0000u;
    return ua | ub;
}
__device__ inline float2 bf2f(unsigned u) {
    float2 r;
    r.x = __uint_as_float(u << 16);
    r.y = __uint_as_float(u & 0xffff0000u);
    return r;
}

// ---------------------------------------------------------------------------
// x (fp32) -> hx[i].y (bf16 pair). One uint per thread, 3.2M threads.
// hx layout: uint2 per (node,lane-slot): .x = ha_src pair (GEMM fills),
// .y = x pair. Row pitch = 64 slots = 512 B.
// ---------------------------------------------------------------------------
__global__ __launch_bounds__(256) void k_cvt(const float* __restrict__ x,
                                             uint2* __restrict__ hx)
{
    int i = blockIdx.x * 256 + threadIdx.x;    // < NF/2
    float2 v = ((const float2*)x)[i];
    unsigned* p = (unsigned*)hx;
    p[i * 2 + 1] = f2bf2(v.x, v.y);
}

// ---------------------------------------------------------------------------
// Weights -> whT bf16, n-major k-contiguous: whT[n][kk] uint holds
// W[2kk][n] (low) | W[2kk+1][n] (high); n<128: src_w, n>=128: dst_w.
// ---------------------------------------------------------------------------
__global__ __launch_bounds__(256) void k_cvtw(const float* __restrict__ src_w,
                                              const float* __restrict__ dst_w,
                                              unsigned* __restrict__ whT)
{
    int i = blockIdx.x * 256 + threadIdx.x;    // < 256*64 = 16384
    int n = i >> 6;
    int kk = i & 63;
    const float* W = (n < 128) ? src_w : dst_w;
    int col = n & 127;
    float w0 = W[(2 * kk) * DIM + col];
    float w1 = W[(2 * kk + 1) * DIM + col];
    whT[i] = f2bf2(w0, w1);
}

// ---------------------------------------------------------------------------
// CSR build: histogram -> 3-kernel exclusive scan -> scatter.
// After k_scatter, rs[n] = END of node n's segment.
// ---------------------------------------------------------------------------
__global__ __launch_bounds__(256) void k_hist(const int* __restrict__ dst,
                                              int* __restrict__ deg)
{
    int e = blockIdx.x * 256 + threadIdx.x;
    if (e < N_EDGES) atomicAdd(&deg[dst[e]], 1);
}

__global__ __launch_bounds__(256) void k_scan1(const int* __restrict__ deg,
                                               int* __restrict__ bsum)
{
    __shared__ int sm[256];
    int t = threadIdx.x;
    int i = blockIdx.x * 256 + t;
    sm[t] = (i < N_NODES) ? deg[i] : 0;
    __syncthreads();
    for (int o = 128; o > 0; o >>= 1) {
        if (t < o) sm[t] += sm[t + o];
        __syncthreads();
    }
    if (t == 0) bsum[blockIdx.x] = sm[0];
}

__global__ __launch_bounds__(256) void k_scan2(int* __restrict__ bsum)
{
    __shared__ int sm[256];
    int t = threadIdx.x;
    int v = (t < NB) ? bsum[t] : 0;
    sm[t] = v;
    __syncthreads();
    for (int o = 1; o < 256; o <<= 1) {
        int u = (t >= o) ? sm[t - o] : 0;
        __syncthreads();
        sm[t] += u;
        __syncthreads();
    }
    if (t < NB) bsum[t] = sm[t] - v;
}

__global__ __launch_bounds__(256) void k_scan3(const int* __restrict__ deg,
                                               const int* __restrict__ bsum,
                                               int* __restrict__ rs)
{
    __shared__ int sm[256];
    int t = threadIdx.x;
    int i = blockIdx.x * 256 + t;
    int v = (i < N_NODES) ? deg[i] : 0;
    sm[t] = v;
    __syncthreads();
    for (int o = 1; o < 256; o <<= 1) {
        int u = (t >= o) ? sm[t - o] : 0;
        __syncthreads();
        sm[t] += u;
        __syncthreads();
    }
    if (i < N_NODES) rs[i] = bsum[blockIdx.x] + sm[t] - v;
}

__global__ __launch_bounds__(256) void k_scatter(const int* __restrict__ src,
                                                 const int* __restrict__ dst,
                                                 int* __restrict__ rs,
                                                 int* __restrict__ srcs)
{
    int e = blockIdx.x * 256 + threadIdx.x;
    if (e >= N_EDGES) return;
    int pos = atomicAdd(&rs[dst[e]], 1);
    srcs[pos] = src[e];
}

// ---------------------------------------------------------------------------
// MFMA GEMM: [ha_src | y] = x @ [src_w | dst_w] (+ src_b on first half).
// One wave per 16 rows, N=256, K=128. A converted fp32->bf16 in-register;
// B read from whT (64 KB, L2-resident). 16 n-tiles x 4 k-steps of
// mfma_f32_16x16x32_bf16. ha_src -> hx[row][slot].x (interleaved bf16),
// y -> separate bf16 array.
// ---------------------------------------------------------------------------
__global__ __launch_bounds__(256) void k_gemm(
    const float* __restrict__ x, const unsigned* __restrict__ whT,
    const float* __restrict__ src_b, unsigned short* __restrict__ hx_us,
    unsigned short* __restrict__ y_us)
{
    int wave = threadIdx.x >> 6;
    int lane = threadIdx.x & 63;
    int quad = lane >> 4;
    int m = lane & 15;
    int m0 = blockIdx.x * 64 + wave * 16;
    int arow = m0 + m;

    // A fragments: a[k0] = bf16(x[arow][k0*32 + quad*8 + j]), j=0..7
    v8s a[4];
    #pragma unroll
    for (int k0 = 0; k0 < 4; ++k0) {
        float4 f0 = make_float4(0.f, 0.f, 0.f, 0.f);
        float4 f1 = f0;
        if (arow < N_NODES) {
            const float4* xp = (const float4*)(x + (size_t)arow * DIM + k0 * 32 + quad * 8);
            f0 = xp[0];
            f1 = xp[1];
        }
        union { unsigned u[4]; v8s s; } pk;
        pk.u[0] = f2bf2(f0.x, f0.y);
        pk.u[1] = f2bf2(f0.z, f0.w);
        pk.u[2] = f2bf2(f1.x, f1.y);
        pk.u[3] = f2bf2(f1.z, f1.w);
        a[k0] = pk.s;
    }

    #pragma unroll
    for (int nt = 0; nt < 16; ++nt) {
        v4f acc = {0.f, 0.f, 0.f, 0.f};
        const uint4* bp = (const uint4*)(whT + ((size_t)(nt * 16 + m)) * 64 + quad * 4);
        #pragma unroll
        for (int k0 = 0; k0 < 4; ++k0) {
            union { uint4 u; v8s s; } b;
            b.u = bp[k0 * 4];   // + k0*16 uints
            acc = __builtin_amdgcn_mfma_f32_16x16x32_bf16(a[k0], b.s, acc, 0, 0, 0);
        }
        // epilogue: D row = m0 + quad*4 + r, col = nt*16 + m
        int c = nt * 16 + m;
        float bias = (c < DIM) ? src_b[c] : 0.f;
        #pragma unroll
        for (int r = 0; r < 4; ++r) {
            int row = m0 + quad * 4 + r;
            if (row < N_NODES) {
                unsigned short h = f2bf(acc[r] + bias);
                if (c < DIM) {
                    // hx: 256 ushorts/row; slot c>>1, .x halves at +0/+1
                    hx_us[(size_t)row * 256 + (c >> 1) * 4 + (c & 1)] = h;
                } else {
                    y_us[(size_t)row * DIM + (c - DIM)] = h;
                }
            }
        }
    }
}

// ---------------------------------------------------------------------------
// Fused: pass1 ha_dst[node] = mean(y[src]) + dst_b (registers);
// pass2 scores + edge softmax + weighted aggregation. One wave per node.
// ---------------------------------------------------------------------------
__global__ __launch_bounds__(256) void k_fuse(
    const uint2* __restrict__ hx, const unsigned* __restrict__ yu,
    const int* __restrict__ srcs, const int* __restrict__ rs_end,
    const int* __restrict__ deg, const float* __restrict__ dst_b,
    const float* __restrict__ att_w, const float* __restrict__ att_b,
    float* __restrict__ out)
{
    int g = blockIdx.x * 256 + threadIdx.x;
    int node = g >> 6;
    int lane = g & 63;
    int end = rs_end[node];
    int cnt = deg[node];
    float2 o2 = make_float2(0.f, 0.f);
    if (cnt == 0) {
        ((float2*)out)[node * 64 + lane] = o2;
        return;
    }
    int start = end - cnt;

    // ---- pass 1: ha_dst row = mean(y[src]) + dst_b --------------------------
    float2 hd = make_float2(0.f, 0.f);
    {
        int i = start;
        for (; i + 3 < end; i += 4) {
            float2 a = bf2f(yu[srcs[i] * 64 + lane]);
            float2 b = bf2f(yu[srcs[i + 1] * 64 + lane]);
            float2 c = bf2f(yu[srcs[i + 2] * 64 + lane]);
            float2 d = bf2f(yu[srcs[i + 3] * 64 + lane]);
            hd.x += (a.x + b.x) + (c.x + d.x);
            hd.y += (a.y + b.y) + (c.y + d.y);
        }
        for (; i < end; ++i) {
            float2 a = bf2f(yu[srcs[i] * 64 + lane]);
            hd.x += a.x;
            hd.y += a.y;
        }
        float inv = 1.0f / (float)cnt;
        float2 db = ((const float2*)dst_b)[lane];
        hd.x = hd.x * inv + db.x;
        hd.y = hd.y * inv + db.y;
    }

    // ---- pass 2: scores + softmax + weighted sum ----------------------------
    float2 aw = ((const float2*)att_w)[lane];
    float ab = att_b[0];
    float dsum = 0.f;
    int i = start;
    for (; i + 3 < end; i += 4) {
        uint2 q0 = hx[srcs[i] * 64 + lane];
        uint2 q1 = hx[srcs[i + 1] * 64 + lane];
        uint2 q2 = hx[srcs[i + 2] * 64 + lane];
        uint2 q3 = hx[srcs[i + 3] * 64 + lane];
        float2 h0 = bf2f(q0.x), h1 = bf2f(q1.x), h2 = bf2f(q2.x), h3 = bf2f(q3.x);
        float v;
        float p0, p1, p2, p3;
        v = h0.x + hd.x; v = (v > 0.f) ? v : v * NEG_SLOPE; p0 = v * aw.x;
        v = h0.y + hd.y; v = (v > 0.f) ? v : v * NEG_SLOPE; p0 += v * aw.y;
        v = h1.x + hd.x; v = (v > 0.f) ? v : v * NEG_SLOPE; p1 = v * aw.x;
        v = h1.y + hd.y; v = (v > 0.f) ? v : v * NEG_SLOPE; p1 += v * aw.y;
        v = h2.x + hd.x; v = (v > 0.f) ? v : v * NEG_SLOPE; p2 = v * aw.x;
        v = h2.y + hd.y; v = (v > 0.f) ? v : v * NEG_SLOPE; p2 += v * aw.y;
        v = h3.x + hd.x; v = (v > 0.f) ? v : v * NEG_SLOPE; p3 = v * aw.x;
        v = h3.y + hd.y; v = (v > 0.f) ? v : v * NEG_SLOPE; p3 += v * aw.y;
        p0 += __shfl_xor(p0, 32); p1 += __shfl_xor(p1, 32);
        p2 += __shfl_xor(p2, 32); p3 += __shfl_xor(p3, 32);
        p0 += __shfl_xor(p0, 16); p1 += __shfl_xor(p1, 16);
        p2 += __shfl_xor(p2, 16); p3 += __shfl_xor(p3, 16);
        p0 += __shfl_xor(p0, 8);  p1 += __shfl_xor(p1, 8);
        p2 += __shfl_xor(p2, 8);  p3 += __shfl_xor(p3, 8);
        p0 += __shfl_xor(p0, 4);  p1 += __shfl_xor(p1, 4);
        p2 += __shfl_xor(p2, 4);  p3 += __shfl_xor(p3, 4);
        p0 += __shfl_xor(p0, 2);  p1 += __shfl_xor(p1, 2);
        p2 += __shfl_xor(p2, 2);  p3 += __shfl_xor(p3, 2);
        p0 += __shfl_xor(p0, 1);  p1 += __shfl_xor(p1, 1);
        p2 += __shfl_xor(p2, 1);  p3 += __shfl_xor(p3, 1);
        float s0 = __expf(p0 + ab);
        float s1 = __expf(p1 + ab);
        float s2 = __expf(p2 + ab);
        float s3 = __expf(p3 + ab);
        float2 x0 = bf2f(q0.y), x1 = bf2f(q1.y), x2 = bf2f(q2.y), x3 = bf2f(q3.y);
        o2.x += s0 * x0.x + s1 * x1.x + s2 * x2.x + s3 * x3.x;
        o2.y += s0 * x0.y + s1 * x1.y + s2 * x2.y + s3 * x3.y;
        dsum += (s0 + s1) + (s2 + s3);
    }
    for (; i < end; ++i) {
        uint2 q0 = hx[srcs[i] * 64 + lane];
        float2 h0 = bf2f(q0.x);
        float v;
        float p0;
        v = h0.x + hd.x; v = (v > 0.f) ? v : v * NEG_SLOPE; p0 = v * aw.x;
        v = h0.y + hd.y; v = (v > 0.f) ? v : v * NEG_SLOPE; p0 += v * aw.y;
        p0 += __shfl_xor(p0, 32);
        p0 += __shfl_xor(p0, 16);
        p0 += __shfl_xor(p0, 8);
        p0 += __shfl_xor(p0, 4);
        p0 += __shfl_xor(p0, 2);
        p0 += __shfl_xor(p0, 1);
        float s0 = __expf(p0 + ab);
        float2 x0 = bf2f(q0.y);
        o2.x += s0 * x0.x;
        o2.y += s0 * x0.y;
        dsum += s0;
    }
    float inv = 1.0f / dsum;
    o2.x *= inv;
    o2.y *= inv;
    ((float2*)out)[node * 64 + lane] = o2;
}

// ---------------------------------------------------------------------------
extern "C" void kernel_launch(void* const* d_in, const int* in_sizes, int n_in,
                              void* d_out, int out_size, void* d_ws, size_t ws_size,
                              hipStream_t stream)
{
    const float* x     = (const float*)d_in[0];
    const int*   src   = (const int*)d_in[1];
    const int*   dst   = (const int*)d_in[2];
    const float* src_w = (const float*)d_in[3];
    const float* src_b = (const float*)d_in[4];
    const float* dst_w = (const float*)d_in[5];
    const float* dst_b = (const float*)d_in[6];
    const float* att_w = (const float*)d_in[7];
    const float* att_b = (const float*)d_in[8];
    float* out = (float*)d_out;
    (void)in_sizes; (void)n_in; (void)out_size; (void)ws_size;

    const size_t NF = (size_t)N_NODES * DIM;   // 6.4M

    // workspace layout (ints; hx kept 8-B aligned)
    int* ws = (int*)d_ws;
    int* ideg = ws;                               // 50,000
    int* rs   = ws + 50000;                       // 50,000
    int* bsum = ws + 100000;                      // 200 (padded)
    int* srcs = ws + 100200;                      // 800,000
    unsigned* whT = (unsigned*)(ws + 900200);     // 16,384 uints
    unsigned* yu  = whT + 16384;                  // 3.2M uints (y bf16)
    uint2*    hx  = (uint2*)(yu + NF / 2);        // 3.2M uint2 (ha_s|x bf16)

    hipMemsetAsync(ideg, 0, N_NODES * sizeof(int), stream);

    // bf16 conversions
    k_cvt <<<(int)(NF / 2 / 256), 256, 0, stream>>>(x, hx);
    k_cvtw<<<64, 256, 0, stream>>>(src_w, dst_w, whT);

    // CSR build
    k_hist   <<<N_EDGES / 256, 256, 0, stream>>>(dst, ideg);
    k_scan1  <<<NB, 256, 0, stream>>>(ideg, bsum);
    k_scan2  <<<1, 256, 0, stream>>>(bsum);
    k_scan3  <<<NB, 256, 0, stream>>>(ideg, bsum, rs);
    k_scatter<<<N_EDGES / 256, 256, 0, stream>>>(src, dst, rs, srcs);

    // fused projection GEMM (MFMA): [ha_src | y] = x @ [src_w | dst_w]
    k_gemm<<<(N_NODES + 63) / 64, 256, 0, stream>>>(
        x, whT, src_b, (unsigned short*)hx, (unsigned short*)yu);

    // fused mean + score + softmax + weighted aggregation
    k_fuse<<<N_NODES * 64 / 256, 256, 0, stream>>>(
        hx, yu, srcs, rs, ideg, dst_b, att_w, att_b, out);
}